// Round 8
// baseline (89.695 us; speedup 1.0000x reference)
//
#include <hip/hip_runtime.h>

typedef __attribute__((ext_vector_type(8))) short          bf16x8;   // MFMA A/B frag
typedef __attribute__((ext_vector_type(8))) unsigned short u16x8;
typedef __attribute__((ext_vector_type(4))) float          f32x4;    // MFMA C/D frag

#define Bn 16
#define IC 32
#define OC 64
#define Hh 128
#define Ww 128
#define ROWS 4            // output rows per block
#define INROWS (ROWS + 2) // staged rows incl. halo
#define CP 132            // padded col count; LDS col = gx+1, cols 0..129 used

__device__ inline unsigned short f2b(float f) {
    unsigned u = __builtin_bit_cast(unsigned, f);
    return (unsigned short)((u + 0x7FFFu + ((u >> 16) & 1u)) >> 16);
}

__device__ inline unsigned cvtpk(float a, float b) {
    unsigned r;
    asm("v_cvt_pk_bf16_f32 %0, %1, %2" : "=v"(r) : "v"(a), "v"(b));
    return r;
}

// ---- prep: w OIHW fp32 -> bf16 [dydx][oc][ic] frag table (36 KB, L2) ----
__global__ void prep_w(const float* __restrict__ w, unsigned short* __restrict__ wf)
{
    int idx = blockIdx.x * 256 + threadIdx.x;        // 0 .. 18431
    int dydx = idx / (OC * IC);
    int rem  = idx - dydx * (OC * IC);               // oc*32 + ic
    wf[idx] = f2b(w[(size_t)rem * 9 + dydx]);
}

// ---- fused conv, 8 waves/block, oc-split for 4 waves/SIMD occupancy ----
// wave wid: strip = wid>>1 (32-pixel column strip), oc_half = wid&1 (32 oc).
// bw shrinks to 9x2 frags (72 VGPR) -> fits 128-VGPR budget -> 2x TLP.
__global__ __launch_bounds__(512, 4)
void conv_fused(const float* __restrict__ x,
                const unsigned short* __restrict__ wf,
                const float* __restrict__ bias,
                float* __restrict__ out)
{
    __shared__ __align__(16) unsigned short xs[INROWS * 4 * CP * 8]; // 50688 B
    __shared__ float sm[ROWS * 4 * 2 * 32];                          // 4 KB

    const int tid  = threadIdx.x;
    const int lane = tid & 63;
    const int wid  = tid >> 6;          // 0..7
    const int llo  = lane & 15;
    const int lhi  = lane >> 4;
    const int strip   = wid >> 1;       // 0..3
    const int oc_half = wid & 1;        // 0..1
    const int b    = blockIdx.y;
    const int y0   = blockIdx.x * ROWS;

    // zero halo columns (gx = -1 -> col 0, gx = 128 -> col 129)
    if (tid < 48) {
        int r = tid >> 3, rest = tid & 7;
        int icg = rest & 3;
        int col = (rest >> 2) ? 129 : 0;
        *(u16x8*)&xs[((r * 4 + icg) * CP + col) * 8] = (u16x8){0,0,0,0,0,0,0,0};
    }

    // ---- stage x: 768 tasks over 512 threads (waves 4..7 skip 2nd, uniform) ----
    const float* xb0 = x + (size_t)b * IC * Hh * Ww;
    #pragma unroll
    for (int i = 0; i < 2; ++i) {
        int task = tid + i * 512;
        if (task < INROWS * 4 * 32) {                // 768
            int cg   = task & 31;                    // 4-col group
            int icg  = (task >> 5) & 3;
            int row  = task >> 7;
            int gy   = y0 - 1 + row;
            int col0 = cg * 4;

            f32x4 v[8];
            if ((unsigned)gy < 128u) {
                const float* sp = xb0 + ((size_t)(icg * 8) * Hh + gy) * Ww + col0;
                #pragma unroll
                for (int j = 0; j < 8; ++j)
                    v[j] = *(const f32x4*)(sp + (size_t)j * Hh * Ww);
            } else {
                #pragma unroll
                for (int j = 0; j < 8; ++j) v[j] = (f32x4){0.f, 0.f, 0.f, 0.f};
            }

            unsigned short* base = &xs[((row * 4 + icg) * CP + col0 + 1) * 8];
            #pragma unroll
            for (int c = 0; c < 4; ++c) {
                unsigned pk[4];
                #pragma unroll
                for (int jp = 0; jp < 4; ++jp)
                    pk[jp] = cvtpk(v[2 * jp][c], v[2 * jp + 1][c]);
                *(u16x8*)(base + c * 8) = *(const u16x8*)&pk[0];
            }
        }
    }

    // ---- B-fragments for this wave's oc-half (L2-resident table) ----
    bf16x8 bw[9][2];
    #pragma unroll
    for (int dydx = 0; dydx < 9; ++dydx)
        #pragma unroll
        for (int nf = 0; nf < 2; ++nf)
            bw[dydx][nf] = *(const bf16x8*)&wf[((size_t)(dydx * OC + oc_half * 32 + nf * 16 + llo)) * IC + lhi * 8];

    float bias_s[2];
    #pragma unroll
    for (int nf = 0; nf < 2; ++nf) bias_s[nf] = bias[oc_half * 32 + nf * 16 + llo];

    __syncthreads();

    const int px0 = strip * 32;
    for (int r = 0; r < ROWS; ++r) {
        f32x4 acc[2][2];
        #pragma unroll
        for (int m = 0; m < 2; ++m)
            #pragma unroll
            for (int nf = 0; nf < 2; ++nf)
                acc[m][nf] = (f32x4){0.f, 0.f, 0.f, 0.f};

        #pragma unroll
        for (int dy = 0; dy < 3; ++dy) {
            #pragma unroll
            for (int dx = 0; dx < 3; ++dx) {
                const int dydx = dy * 3 + dx;
                bf16x8 a0 = *(const bf16x8*)&xs[(((r + dy) * 4 + lhi) * CP + px0 + llo + dx) * 8];
                bf16x8 a1 = *(const bf16x8*)&xs[(((r + dy) * 4 + lhi) * CP + px0 + 16 + llo + dx) * 8];
                #pragma unroll
                for (int nf = 0; nf < 2; ++nf) {
                    acc[0][nf] = __builtin_amdgcn_mfma_f32_16x16x32_bf16(a0, bw[dydx][nf], acc[0][nf], 0, 0, 0);
                    acc[1][nf] = __builtin_amdgcn_mfma_f32_16x16x32_bf16(a1, bw[dydx][nf], acc[1][nf], 0, 0, 0);
                }
            }
        }

        // in-wave: bias + min over this oc-half (2 frags + shfl over 16 oc-lanes)
        #pragma unroll
        for (int m = 0; m < 2; ++m) {
            f32x4 vout;
            #pragma unroll
            for (int j = 0; j < 4; ++j) {
                float v = fminf(acc[m][0][j] + bias_s[0], acc[m][1][j] + bias_s[1]);
                v = fminf(v, __shfl_xor(v, 1, 64));
                v = fminf(v, __shfl_xor(v, 2, 64));
                v = fminf(v, __shfl_xor(v, 4, 64));
                v = fminf(v, __shfl_xor(v, 8, 64));
                vout[j] = v;
            }
            if (llo == 0)
                *(f32x4*)&sm[((r * 4 + strip) * 2 + oc_half) * 32 + m * 16 + lhi * 4] = vout;
        }
    }

    __syncthreads();

    // ---- combine oc-halves, scale, coalesced store: 512 threads, 1 px each ----
    {
        int r   = tid >> 7;          // 0..3
        int col = tid & 127;
        int st  = col >> 5, p = col & 31;
        float v0 = sm[((r * 4 + st) * 2 + 0) * 32 + p];
        float v1 = sm[((r * 4 + st) * 2 + 1) * 32 + p];
        out[((size_t)b * Hh + y0 + r) * Ww + col] = fminf(v0, v1) * 2.0f;
    }
}

extern "C" void kernel_launch(void* const* d_in, const int* in_sizes, int n_in,
                              void* d_out, int out_size, void* d_ws, size_t ws_size,
                              hipStream_t stream)
{
    const float* x    = (const float*)d_in[0];
    const float* w    = (const float*)d_in[1];
    const float* bias = (const float*)d_in[2];
    float* out        = (float*)d_out;

    unsigned short* wfr = (unsigned short*)d_ws;      // 36 KB frag table

    prep_w<<<dim3(9 * OC * IC / 256), 256, 0, stream>>>(w, wfr);
    conv_fused<<<dim3(Hh / ROWS, Bn), 512, 0, stream>>>(x, wfr, bias, out);
}